// Round 17
// baseline (95.024 us; speedup 1.0000x reference)
//
#include <hip/hip_runtime.h>
#include <hip/hip_bf16.h>
#include <hip/hip_fp16.h>

// SASA local self-attention. Round 17: PHASE ABLATION round.
//  V0: full r16 kernel -> d_out (unchanged, correct).
//  V1: projection-only (stage+proj+qproj), checksum -> ws. Measures projection cost.
//  V2: attention-only (garbage K/V from regs, no global reads), checksum -> ws.
// Per-dispatch rocprof durations give the phase split.
// B=4, CIN=COUT=256, H=W=64, G=8, CG=32, K=7, PAD=3.
#define TS   16
#define HS   22
#define HP   484
#define KDW  18
#define KK   7
#define K2   49

typedef _Float16 h2 __attribute__((ext_vector_type(2)));
union U32H { unsigned u; h2 h; __half2 p; };

__device__ __forceinline__ h2 pkrtz(float a, float b) {
    auto r = __builtin_amdgcn_cvt_pkrtz(a, b);
    union { decltype(r) i; h2 o; } c; c.i = r;
    return c.o;
}
__device__ __forceinline__ float dot2(h2 a, h2 b, float c) {
#if __has_builtin(__builtin_amdgcn_fdot2)
    return __builtin_amdgcn_fdot2(a, b, c, false);
#else
    return fmaf((float)a.x, (float)b.x, fmaf((float)a.y, (float)b.y, c));
#endif
}
__device__ __forceinline__ float dot2u(unsigned wu, h2 b, float c) {
    U32H w; w.u = wu; return dot2(w.h, b, c);
}
__device__ __forceinline__ float pswap(float v) {
#if __has_builtin(__builtin_amdgcn_mov_dpp)
    int j = __builtin_amdgcn_mov_dpp(__float_as_int(v), 0xB1, 0xF, 0xF, true);
    return __int_as_float(j);
#else
    return __shfl_xor(v, 1, 64);
#endif
}

template<int V>
__global__ __attribute__((amdgpu_flat_work_group_size(512, 512), amdgpu_waves_per_eu(4, 4)))
void sasa_k(const float* __restrict__ x,
            const float* __restrict__ wq,
            const float* __restrict__ wk,
            const float* __restrict__ wv,
            const float* __restrict__ row_emb,
            const float* __restrict__ col_emb,
            float* __restrict__ out,
            float* __restrict__ ws)
{
    __shared__ h2       s_w[1536];
    __shared__ float    s_emb[224];
    __shared__ unsigned s_ku[HP * KDW];
    __shared__ unsigned s_vu[HP * KDW];

    const int tid = threadIdx.x;

    const int lin  = blockIdx.x + (blockIdx.y << 2) + (blockIdx.z << 4);
    const int xcd  = lin & 7;
    const int slot = lin >> 3;
    const int zg   = xcd + ((slot >> 4) << 3);
    const int sp   = slot & 15;
    const int b    = zg >> 3;
    const int g    = zg & 7;
    const int y0   = (sp >> 2) * TS;
    const int x0   = (sp & 3) * TS;

    const int p  = tid >> 1;
    const int h  = tid & 1;
    const int tx = p & 15, ty = p >> 4;
    const int yy = y0 + ty, xx = x0 + tx;

    const float* xg = x + (size_t)(b * 256 + g * 32) * 4096;

    float qe[KK];
    h2 q2[8];

    if constexpr (V != 2) {
        // ---- pre-issue projection x loads (both items) ----
        const int hh0 = (tid >= HP) ? 1 : 0;
        const int hp0 = tid - (hh0 ? HP : 0);
        const int hy0 = hp0 / HS, hx0 = hp0 - hy0 * HS;
        const int gy0 = y0 + hy0 - 3, gx0 = x0 + hx0 - 3;
        const bool ok0 = ((unsigned)gy0 < 64u) && ((unsigned)gx0 < 64u);

        const int hp1 = tid + 28;
        const int hy1 = hp1 / HS, hx1 = hp1 - hy1 * HS;
        const int gy1 = y0 + hy1 - 3, gx1 = x0 + hx1 - 3;
        const bool it1v = (tid < 2 * HP - 512);
        const bool ok1 = it1v && ((unsigned)gy1 < 64u) && ((unsigned)gx1 < 64u);

        float xr0[32], xr1[32];
        #pragma unroll
        for (int ci = 0; ci < 32; ++ci) { xr0[ci] = 0.f; xr1[ci] = 0.f; }
        if (ok0) {
            const float* xp = xg + gy0 * 64 + gx0;
            #pragma unroll
            for (int ci = 0; ci < 32; ++ci) xr0[ci] = xp[ci * 4096];
        }
        if (ok1) {
            const float* xp = xg + gy1 * 64 + gx1;
            #pragma unroll
            for (int ci = 0; ci < 32; ++ci) xr1[ci] = xp[ci * 4096];
        }

        // ---- stage weights + emb ----
        {
            const int cp  = tid & 15;
            const int cog = tid >> 4;
            const int hh  = cog >> 4;
            const int co  = cog & 15;
            const int di  = (hh * 16 + cp) * 16 + co;
            const float2* wk2 = (const float2*)(wk + g * 1024);
            const float2* wv2 = (const float2*)(wv + g * 1024);
            const float2* wq2 = (const float2*)(wq + g * 1024);
            float2 a = wk2[tid]; s_w[di]        = pkrtz(a.x, a.y);
            float2 v = wv2[tid]; s_w[512 + di]  = pkrtz(v.x, v.y);
            float2 q = wq2[tid]; s_w[1024 + di] = pkrtz(q.x, q.y);
        }
        if (tid < 224) {
            int c = tid / KK, t = tid - c * KK;
            s_emb[tid] = (g < 4) ? row_emb[(g * 32 + c) * KK + t]
                                 : col_emb[((g - 4) * 32 + c) * KK + t];
        }
        __syncthreads();

        // ---- item0 projection ----
        {
            h2 xv2[16];
            #pragma unroll
            for (int cp = 0; cp < 16; ++cp) xv2[cp] = pkrtz(xr0[2 * cp], xr0[2 * cp + 1]);
            float accK[16], accV[16];
            #pragma unroll
            for (int c = 0; c < 16; ++c) { accK[c] = 0.f; accV[c] = 0.f; }
            const h2* wkp = s_w + hh0 * 256;
            const h2* wvp = s_w + 512 + hh0 * 256;
            #pragma unroll
            for (int cp = 0; cp < 16; ++cp) {
                h2 xv = xv2[cp];
                const uint4* wkr = (const uint4*)(wkp + cp * 16);
                const uint4* wvr = (const uint4*)(wvp + cp * 16);
                uint4 kw[4] = { wkr[0], wkr[1], wkr[2], wkr[3] };
                uint4 vw[4] = { wvr[0], wvr[1], wvr[2], wvr[3] };
                const unsigned* kwu = (const unsigned*)kw;
                const unsigned* vwu = (const unsigned*)vw;
                #pragma unroll
                for (int co = 0; co < 16; ++co) {
                    accK[co] = dot2u(kwu[co], xv, accK[co]);
                    accV[co] = dot2u(vwu[co], xv, accV[co]);
                }
            }
            unsigned* dk = s_ku + hp0 * KDW + hh0 * 8;
            unsigned* dv = s_vu + hp0 * KDW + hh0 * 8;
            #pragma unroll
            for (int j = 0; j < 4; ++j) {
                U32H a0, a1, b0, b1;
                a0.h = pkrtz(accK[4 * j],     accK[4 * j + 1]);
                a1.h = pkrtz(accK[4 * j + 2], accK[4 * j + 3]);
                b0.h = pkrtz(accV[4 * j],     accV[4 * j + 1]);
                b1.h = pkrtz(accV[4 * j + 2], accV[4 * j + 3]);
                ((uint2*)dk)[j] = make_uint2(a0.u, a1.u);
                ((uint2*)dv)[j] = make_uint2(b0.u, b1.u);
            }
        }
        // ---- item1 projection ----
        if (it1v) {
            h2 xv2[16];
            #pragma unroll
            for (int cp = 0; cp < 16; ++cp) xv2[cp] = pkrtz(xr1[2 * cp], xr1[2 * cp + 1]);
            float accK[16], accV[16];
            #pragma unroll
            for (int c = 0; c < 16; ++c) { accK[c] = 0.f; accV[c] = 0.f; }
            const h2* wkp = s_w + 256;
            const h2* wvp = s_w + 512 + 256;
            #pragma unroll
            for (int cp = 0; cp < 16; ++cp) {
                h2 xv = xv2[cp];
                const uint4* wkr = (const uint4*)(wkp + cp * 16);
                const uint4* wvr = (const uint4*)(wvp + cp * 16);
                uint4 kw[4] = { wkr[0], wkr[1], wkr[2], wkr[3] };
                uint4 vw[4] = { wvr[0], wvr[1], wvr[2], wvr[3] };
                const unsigned* kwu = (const unsigned*)kw;
                const unsigned* vwu = (const unsigned*)vw;
                #pragma unroll
                for (int co = 0; co < 16; ++co) {
                    accK[co] = dot2u(kwu[co], xv, accK[co]);
                    accV[co] = dot2u(vwu[co], xv, accV[co]);
                }
            }
            unsigned* dk = s_ku + hp1 * KDW + 8;
            unsigned* dv = s_vu + hp1 * KDW + 8;
            #pragma unroll
            for (int j = 0; j < 4; ++j) {
                U32H a0, a1, b0, b1;
                a0.h = pkrtz(accK[4 * j],     accK[4 * j + 1]);
                a1.h = pkrtz(accK[4 * j + 2], accK[4 * j + 3]);
                b0.h = pkrtz(accV[4 * j],     accV[4 * j + 1]);
                b1.h = pkrtz(accV[4 * j + 2], accV[4 * j + 3]);
                ((uint2*)dk)[j] = make_uint2(a0.u, a1.u);
                ((uint2*)dv)[j] = make_uint2(b0.u, b1.u);
            }
        }

        // ---- q projection ----
        float accQ[16];
        #pragma unroll
        for (int c = 0; c < 16; ++c) accQ[c] = 0.f;
        {
            const float* xp = xg + yy * 64 + xx;
            h2 xv2[16];
            #pragma unroll
            for (int cp = 0; cp < 16; ++cp)
                xv2[cp] = pkrtz(xp[(2 * cp) * 4096], xp[(2 * cp + 1) * 4096]);
            const h2* wqp = s_w + 1024 + h * 256;
            #pragma unroll
            for (int cp = 0; cp < 16; ++cp) {
                h2 xv = xv2[cp];
                const uint4* wqr = (const uint4*)(wqp + cp * 16);
                uint4 qw[4] = { wqr[0], wqr[1], wqr[2], wqr[3] };
                const unsigned* qwu = (const unsigned*)qw;
                #pragma unroll
                for (int co = 0; co < 16; ++co)
                    accQ[co] = dot2u(qwu[co], xv, accQ[co]);
            }
        }

        #pragma unroll
        for (int t = 0; t < KK; ++t) {
            float a = 0.f;
            #pragma unroll
            for (int c = 0; c < 16; ++c)
                a = fmaf(accQ[c], s_emb[(h * 16 + c) * KK + t], a);
            qe[t] = a;
        }
        #pragma unroll
        for (int t = 0; t < KK; ++t)
            qe[t] += pswap(qe[t]);

        #pragma unroll
        for (int j = 0; j < 8; ++j) q2[j] = pkrtz(accQ[2 * j], accQ[2 * j + 1]);
    } else {
        // ---- V2: synthesize staged state from registers (no global reads) ----
        for (int i = tid; i < HP * KDW; i += 512) {
            unsigned gk = 0x3C003C00u ^ ((i & 63u) * 0x00010001u);
            s_ku[i] = gk;
            s_vu[i] = gk ^ 0x00400040u;
        }
        #pragma unroll
        for (int j = 0; j < 8; ++j)
            q2[j] = pkrtz((float)((tid + j) & 15) * 0.05f,
                          (float)((tid ^ j) & 15) * 0.05f);
        #pragma unroll
        for (int t = 0; t < KK; ++t) qe[t] = (float)(t & 3) * 0.1f;
    }

    if constexpr (V == 1) {
        // projection-only: keep LDS state live via readback, then exit
        __syncthreads();
        float cs = (float)(s_ku[tid] & 0xFFFFu) + (float)(s_vu[tid + 7] & 0xFFFFu);
        #pragma unroll
        for (int j = 0; j < 8; ++j) { U32H t; t.h = q2[j]; cs += (float)(t.u & 0xFFu); }
        cs += qe[0] + qe[6];
        ws[(size_t)lin * 512 + tid] = cs;
        return;
    }

    __syncthreads();   // s_ku / s_vu complete

    const int rowsel = (g < 4) ? 1 : 0;

    // ---- Phase A ----
    float lg[K2];
    const unsigned* kb = s_ku + h * 8;
    #pragma unroll
    for (int ki = 0; ki < KK; ++ki) {
        #pragma unroll
        for (int kj = 0; kj < KK; ++kj) {
            const uint2* kp = (const uint2*)(kb + ((ty + ki) * HS + tx + kj) * KDW);
            uint2 a0 = kp[0], a1 = kp[1], a2 = kp[2], a3 = kp[3];
            float p0 = 0.f;
            p0 = dot2u(a0.x, q2[0], p0); p0 = dot2u(a0.y, q2[1], p0);
            p0 = dot2u(a1.x, q2[2], p0); p0 = dot2u(a1.y, q2[3], p0);
            p0 = dot2u(a2.x, q2[4], p0); p0 = dot2u(a2.y, q2[5], p0);
            p0 = dot2u(a3.x, q2[6], p0); p0 = dot2u(a3.y, q2[7], p0);
            lg[ki * KK + kj] = p0 + pswap(p0) + (rowsel ? qe[ki] : qe[kj]);
        }
    }

    // ---- Phase B ----
    float m0 = lg[0], m1 = lg[1], m2 = lg[2], m3 = lg[3];
    #pragma unroll
    for (int t = 4; t < 48; t += 4) {
        m0 = fmaxf(m0, lg[t]);
        m1 = fmaxf(m1, lg[t + 1]);
        m2 = fmaxf(m2, lg[t + 2]);
        m3 = fmaxf(m3, lg[t + 3]);
    }
    const float mx = fmaxf(fmaxf(m0, m1), fmaxf(m2, fmaxf(m3, lg[48])));

    float s0 = 0.f, s1 = 0.f, s2 = 0.f, s3 = 0.f;
    #pragma unroll
    for (int t = 0; t < K2; ++t) {
        float pe = __expf(lg[t] - mx);
        lg[t] = pe;
        if ((t & 3) == 0) s0 += pe;
        else if ((t & 3) == 1) s1 += pe;
        else if ((t & 3) == 2) s2 += pe;
        else s3 += pe;
    }
    const float s = (s0 + s1) + (s2 + s3);

    // ---- PV ----
    __half2 o2[8];
    #pragma unroll
    for (int j = 0; j < 8; ++j) o2[j] = __float2half2_rn(0.f);

    const unsigned* vb = s_vu + h * 8;
    #pragma unroll
    for (int ki = 0; ki < KK; ++ki) {
        #pragma unroll
        for (int kj = 0; kj < KK; ++kj) {
            const uint2* vp = (const uint2*)(vb + ((ty + ki) * HS + tx + kj) * KDW);
            uint2 a0 = vp[0], a1 = vp[1], a2 = vp[2], a3 = vp[3];
            const __half2 pe2 = __float2half2_rn(lg[ki * KK + kj]);
            U32H c0, c1, c2, c3, c4, c5, c6, c7;
            c0.u = a0.x; c1.u = a0.y; c2.u = a1.x; c3.u = a1.y;
            c4.u = a2.x; c5.u = a2.y; c6.u = a3.x; c7.u = a3.y;
            o2[0] = __hfma2(c0.p, pe2, o2[0]);
            o2[1] = __hfma2(c1.p, pe2, o2[1]);
            o2[2] = __hfma2(c2.p, pe2, o2[2]);
            o2[3] = __hfma2(c3.p, pe2, o2[3]);
            o2[4] = __hfma2(c4.p, pe2, o2[4]);
            o2[5] = __hfma2(c5.p, pe2, o2[5]);
            o2[6] = __hfma2(c6.p, pe2, o2[6]);
            o2[7] = __hfma2(c7.p, pe2, o2[7]);
        }
    }

    const float inv = 1.0f / s;
    if constexpr (V == 0) {
        float* op = out + (size_t)(b * 256 + g * 32 + h * 16) * 4096 + yy * 64 + xx;
        #pragma unroll
        for (int j = 0; j < 8; ++j) {
            float2 f = __half22float2(o2[j]);
            op[(2 * j) * 4096]     = f.x * inv;
            op[(2 * j + 1) * 4096] = f.y * inv;
        }
    } else {
        float cs = s;
        #pragma unroll
        for (int j = 0; j < 8; ++j) {
            float2 f = __half22float2(o2[j]);
            cs += f.x + f.y;
        }
        ws[(size_t)(1 << 18) + (size_t)lin * 512 + tid] = cs * inv;
    }
}

extern "C" void kernel_launch(void* const* d_in, const int* in_sizes, int n_in,
                              void* d_out, int out_size, void* d_ws, size_t ws_size,
                              hipStream_t stream) {
    const float* x       = (const float*)d_in[0];
    const float* wq      = (const float*)d_in[1];
    const float* wk      = (const float*)d_in[2];
    const float* wv      = (const float*)d_in[3];
    const float* row_emb = (const float*)d_in[4];
    const float* col_emb = (const float*)d_in[5];
    float* out = (float*)d_out;
    float* ws  = (float*)d_ws;

    dim3 grid(4, 4, 32);
    dim3 block(512);
    sasa_k<0><<<grid, block, 0, stream>>>(x, wq, wk, wv, row_emb, col_emb, out, ws);
    if (ws_size >= (size_t)2 * (1 << 18) * sizeof(float)) {
        sasa_k<1><<<grid, block, 0, stream>>>(x, wq, wk, wv, row_emb, col_emb, out, ws);
        sasa_k<2><<<grid, block, 0, stream>>>(x, wq, wk, wv, row_emb, col_emb, out, ws);
    }
}

// Round 19
// 54.055 us; speedup vs baseline: 1.7579x; 1.7579x over previous
//
#include <hip/hip_runtime.h>
#include <hip/hip_bf16.h>
#include <hip/hip_fp16.h>

// SASA local self-attention. Round 18 resubmit (container died): SPLIT KERNELS.
//  A: projection GEMM x -> K/V/Q (f16 pairs) in d_ws. No halo recompute, 6KB LDS,
//     full occupancy, coalesced I/O.
//  B: attention only. K/V halo staged from ws (pure copy), Q from ws to regs,
//     Phase A/B/PV identical to r16. XCD swizzle kept.
//  Fallback: r16 fused kernel if ws_size too small.
// B=4, CIN=COUT=256, H=W=64, G=8, CG=32, K=7, PAD=3.
#define TS   16
#define HS   22
#define HP   484
#define KDW  18
#define KK   7
#define K2   49

typedef _Float16 h2 __attribute__((ext_vector_type(2)));
union U32H { unsigned u; h2 h; __half2 p; };

__device__ __forceinline__ h2 pkrtz(float a, float b) {
    auto r = __builtin_amdgcn_cvt_pkrtz(a, b);
    union { decltype(r) i; h2 o; } c; c.i = r;
    return c.o;
}
__device__ __forceinline__ float dot2(h2 a, h2 b, float c) {
#if __has_builtin(__builtin_amdgcn_fdot2)
    return __builtin_amdgcn_fdot2(a, b, c, false);
#else
    return fmaf((float)a.x, (float)b.x, fmaf((float)a.y, (float)b.y, c));
#endif
}
__device__ __forceinline__ float dot2u(unsigned wu, h2 b, float c) {
    U32H w; w.u = wu; return dot2(w.h, b, c);
}
__device__ __forceinline__ float pswap(float v) {
#if __has_builtin(__builtin_amdgcn_mov_dpp)
    int j = __builtin_amdgcn_mov_dpp(__float_as_int(v), 0xB1, 0xF, 0xF, true);
    return __int_as_float(j);
#else
    return __shfl_xor(v, 1, 64);
#endif
}

// ---------------- Kernel A: projection GEMM (x -> K,V,Q f16 in ws) ----------------
__global__ __launch_bounds__(512)
void proj_kernel(const float* __restrict__ x,
                 const float* __restrict__ wq,
                 const float* __restrict__ wk,
                 const float* __restrict__ wv,
                 unsigned* __restrict__ kws,
                 unsigned* __restrict__ vws,
                 unsigned* __restrict__ qws)
{
    __shared__ h2 s_w[1536];
    const int tid = threadIdx.x;
    const int bg  = blockIdx.y;          // 0..31 == (b<<3)|g
    const int g   = bg & 7;
    const int b   = bg >> 3;

    {
        const int cp  = tid & 15;
        const int cog = tid >> 4;
        const int hh  = cog >> 4;
        const int co  = cog & 15;
        const int di  = (hh * 16 + cp) * 16 + co;
        float2 a = ((const float2*)(wk + g * 1024))[tid]; s_w[di]        = pkrtz(a.x, a.y);
        float2 v = ((const float2*)(wv + g * 1024))[tid]; s_w[512 + di]  = pkrtz(v.x, v.y);
        float2 q = ((const float2*)(wq + g * 1024))[tid]; s_w[1024 + di] = pkrtz(q.x, q.y);
    }

    const int pxl = tid >> 1;
    const int h   = tid & 1;
    const int px  = blockIdx.x * 256 + pxl;
    const float* xp = x + (size_t)(b * 256 + g * 32) * 4096 + px;

    float xr[32];
    #pragma unroll
    for (int c = 0; c < 32; ++c) xr[c] = xp[c * 4096];

    __syncthreads();

    h2 xv2[16];
    #pragma unroll
    for (int cp = 0; cp < 16; ++cp) xv2[cp] = pkrtz(xr[2 * cp], xr[2 * cp + 1]);

    const size_t obase = ((size_t)bg * 4096 + px) * 16 + h * 8;

    #pragma unroll
    for (int m = 0; m < 3; ++m) {
        float acc[16];
        #pragma unroll
        for (int c = 0; c < 16; ++c) acc[c] = 0.f;
        const h2* wb = s_w + m * 512 + h * 256;
        #pragma unroll
        for (int cp = 0; cp < 16; ++cp) {
            h2 xv = xv2[cp];
            const uint4* wr = (const uint4*)(wb + cp * 16);
            uint4 w[4] = { wr[0], wr[1], wr[2], wr[3] };
            const unsigned* wu = (const unsigned*)w;
            #pragma unroll
            for (int co = 0; co < 16; ++co)
                acc[co] = dot2u(wu[co], xv, acc[co]);
        }
        unsigned* dst = (m == 0 ? kws : (m == 1 ? vws : qws)) + obase;
        U32H r0, r1, r2, r3, r4, r5, r6, r7;
        r0.h = pkrtz(acc[0],  acc[1]);  r1.h = pkrtz(acc[2],  acc[3]);
        r2.h = pkrtz(acc[4],  acc[5]);  r3.h = pkrtz(acc[6],  acc[7]);
        r4.h = pkrtz(acc[8],  acc[9]);  r5.h = pkrtz(acc[10], acc[11]);
        r6.h = pkrtz(acc[12], acc[13]); r7.h = pkrtz(acc[14], acc[15]);
        ((uint4*)dst)[0] = make_uint4(r0.u, r1.u, r2.u, r3.u);
        ((uint4*)dst)[1] = make_uint4(r4.u, r5.u, r6.u, r7.u);
    }
}

// ---------------- Kernel B: attention from staged K/V/Q ----------------
__global__ __attribute__((amdgpu_flat_work_group_size(512, 512), amdgpu_waves_per_eu(4, 4)))
void attn_kernel(const unsigned* __restrict__ kws,
                 const unsigned* __restrict__ vws,
                 const unsigned* __restrict__ qws,
                 const float* __restrict__ row_emb,
                 const float* __restrict__ col_emb,
                 float* __restrict__ out)
{
    __shared__ unsigned s_ku[HP * KDW];
    __shared__ unsigned s_vu[HP * KDW];
    __shared__ h2       s_e2[112];       // [h][j][t] = h*56 + j*7 + t

    const int tid = threadIdx.x;

    const int lin  = blockIdx.x + (blockIdx.y << 2) + (blockIdx.z << 4);
    const int xcd  = lin & 7;
    const int slot = lin >> 3;
    const int zg   = xcd + ((slot >> 4) << 3);
    const int sp   = slot & 15;
    const int b    = zg >> 3;
    const int g    = zg & 7;
    const int y0   = (sp >> 2) * TS;
    const int x0   = (sp & 3) * TS;

    const size_t bgbase = (size_t)zg << 16;   // zg * 4096 * 16

    // ---- stage emb (f16 pairs) ----
    if (tid < 112) {
        const int hh = tid / 56;
        const int r  = tid - hh * 56;
        const int j  = r / 7;
        const int t  = r - j * 7;
        const int c0 = hh * 16 + 2 * j;
        float e0, e1;
        if (g < 4) {
            e0 = row_emb[(g * 32 + c0) * 7 + t];
            e1 = row_emb[(g * 32 + c0 + 1) * 7 + t];
        } else {
            e0 = col_emb[((g - 4) * 32 + c0) * 7 + t];
            e1 = col_emb[((g - 4) * 32 + c0 + 1) * 7 + t];
        }
        s_e2[tid] = pkrtz(e0, e1);
    }

    // ---- stage K/V halo from ws (pure copy, zero-padded) ----
    #pragma unroll 1
    for (int it = tid; it < 2 * HP * 4; it += 512) {
        const int mat  = (it >= HP * 4) ? 1 : 0;
        const int c    = it - mat * HP * 4;
        const int px   = c >> 2;
        const int part = c & 3;
        const int hy = px / HS, hx = px - hy * HS;
        const int gy = y0 + hy - 3, gx = x0 + hx - 3;
        uint4 val = make_uint4(0u, 0u, 0u, 0u);
        if ((unsigned)gy < 64u && (unsigned)gx < 64u) {
            const unsigned* src = (mat ? vws : kws) + bgbase
                                + ((size_t)(gy * 64 + gx)) * 16 + part * 4;
            val = *(const uint4*)src;
        }
        unsigned* s = (mat ? s_vu : s_ku) + px * KDW + (part >> 1) * 8 + (part & 1) * 4;
        ((uint2*)s)[0]   = make_uint2(val.x, val.y);
        *(uint2*)(s + 2) = make_uint2(val.z, val.w);
    }

    // ---- Q load (f16 pairs from ws) ----
    const int p  = tid >> 1;
    const int h  = tid & 1;
    const int tx = p & 15, ty = p >> 4;
    const int yy = y0 + ty, xx = x0 + tx;
    h2 q2[8];
    {
        const unsigned* qsrc = qws + bgbase + ((size_t)(yy * 64 + xx)) * 16 + h * 8;
        uint4 qa = ((const uint4*)qsrc)[0];
        uint4 qb = ((const uint4*)qsrc)[1];
        U32H t0, t1, t2, t3, t4, t5, t6, t7;
        t0.u = qa.x; t1.u = qa.y; t2.u = qa.z; t3.u = qa.w;
        t4.u = qb.x; t5.u = qb.y; t6.u = qb.z; t7.u = qb.w;
        q2[0] = t0.h; q2[1] = t1.h; q2[2] = t2.h; q2[3] = t3.h;
        q2[4] = t4.h; q2[5] = t5.h; q2[6] = t6.h; q2[7] = t7.h;
    }

    __syncthreads();   // s_ku / s_vu / s_e2 ready

    // ---- qe[7] = q . emb (f16 dot2), pair-combined via DPP ----
    float qe[KK];
    #pragma unroll
    for (int t = 0; t < KK; ++t) {
        float a = 0.f;
        #pragma unroll
        for (int j = 0; j < 8; ++j)
            a = dot2(q2[j], s_e2[h * 56 + j * 7 + t], a);
        qe[t] = a;
    }
    #pragma unroll
    for (int t = 0; t < KK; ++t)
        qe[t] += pswap(qe[t]);

    const int rowsel = (g < 4) ? 1 : 0;

    // ---- Phase A: 49 logits ----
    float lg[K2];
    const unsigned* kb = s_ku + h * 8;
    #pragma unroll
    for (int ki = 0; ki < KK; ++ki) {
        #pragma unroll
        for (int kj = 0; kj < KK; ++kj) {
            const uint2* kp = (const uint2*)(kb + ((ty + ki) * HS + tx + kj) * KDW);
            uint2 a0 = kp[0], a1 = kp[1], a2 = kp[2], a3 = kp[3];
            float p0 = 0.f;
            p0 = dot2u(a0.x, q2[0], p0); p0 = dot2u(a0.y, q2[1], p0);
            p0 = dot2u(a1.x, q2[2], p0); p0 = dot2u(a1.y, q2[3], p0);
            p0 = dot2u(a2.x, q2[4], p0); p0 = dot2u(a2.y, q2[5], p0);
            p0 = dot2u(a3.x, q2[6], p0); p0 = dot2u(a3.y, q2[7], p0);
            lg[ki * KK + kj] = p0 + pswap(p0) + (rowsel ? qe[ki] : qe[kj]);
        }
    }

    // ---- Phase B: tree max, independent exps, tree sum ----
    float m0 = lg[0], m1 = lg[1], m2 = lg[2], m3 = lg[3];
    #pragma unroll
    for (int t = 4; t < 48; t += 4) {
        m0 = fmaxf(m0, lg[t]);
        m1 = fmaxf(m1, lg[t + 1]);
        m2 = fmaxf(m2, lg[t + 2]);
        m3 = fmaxf(m3, lg[t + 3]);
    }
    const float mx = fmaxf(fmaxf(m0, m1), fmaxf(m2, fmaxf(m3, lg[48])));

    float s0 = 0.f, s1 = 0.f, s2 = 0.f, s3 = 0.f;
    #pragma unroll
    for (int t = 0; t < K2; ++t) {
        float pe = __expf(lg[t] - mx);
        lg[t] = pe;
        if ((t & 3) == 0) s0 += pe;
        else if ((t & 3) == 1) s1 += pe;
        else if ((t & 3) == 2) s2 += pe;
        else s3 += pe;
    }
    const float s = (s0 + s1) + (s2 + s3);

    // ---- PV ----
    __half2 o2[8];
    #pragma unroll
    for (int j = 0; j < 8; ++j) o2[j] = __float2half2_rn(0.f);

    const unsigned* vb = s_vu + h * 8;
    #pragma unroll
    for (int ki = 0; ki < KK; ++ki) {
        #pragma unroll
        for (int kj = 0; kj < KK; ++kj) {
            const uint2* vp = (const uint2*)(vb + ((ty + ki) * HS + tx + kj) * KDW);
            uint2 a0 = vp[0], a1 = vp[1], a2 = vp[2], a3 = vp[3];
            const __half2 pe2 = __float2half2_rn(lg[ki * KK + kj]);
            U32H c0, c1, c2, c3, c4, c5, c6, c7;
            c0.u = a0.x; c1.u = a0.y; c2.u = a1.x; c3.u = a1.y;
            c4.u = a2.x; c5.u = a2.y; c6.u = a3.x; c7.u = a3.y;
            o2[0] = __hfma2(c0.p, pe2, o2[0]);
            o2[1] = __hfma2(c1.p, pe2, o2[1]);
            o2[2] = __hfma2(c2.p, pe2, o2[2]);
            o2[3] = __hfma2(c3.p, pe2, o2[3]);
            o2[4] = __hfma2(c4.p, pe2, o2[4]);
            o2[5] = __hfma2(c5.p, pe2, o2[5]);
            o2[6] = __hfma2(c6.p, pe2, o2[6]);
            o2[7] = __hfma2(c7.p, pe2, o2[7]);
        }
    }

    const float inv = 1.0f / s;
    float* op = out + (size_t)(b * 256 + g * 32 + h * 16) * 4096 + yy * 64 + xx;
    #pragma unroll
    for (int j = 0; j < 8; ++j) {
        float2 f = __half22float2(o2[j]);
        op[(2 * j) * 4096]     = f.x * inv;
        op[(2 * j + 1) * 4096] = f.y * inv;
    }
}

// ---------------- Fallback: r16 fused kernel (used only if ws too small) ----------------
__global__ __attribute__((amdgpu_flat_work_group_size(512, 512), amdgpu_waves_per_eu(4, 4)))
void sasa_fused_kernel(const float* __restrict__ x,
                       const float* __restrict__ wq,
                       const float* __restrict__ wk,
                       const float* __restrict__ wv,
                       const float* __restrict__ row_emb,
                       const float* __restrict__ col_emb,
                       float* __restrict__ out)
{
    __shared__ h2       s_w[1536];
    __shared__ float    s_emb[224];
    __shared__ unsigned s_ku[HP * KDW];
    __shared__ unsigned s_vu[HP * KDW];

    const int tid = threadIdx.x;

    const int lin  = blockIdx.x + (blockIdx.y << 2) + (blockIdx.z << 4);
    const int xcd  = lin & 7;
    const int slot = lin >> 3;
    const int zg   = xcd + ((slot >> 4) << 3);
    const int sp   = slot & 15;
    const int b    = zg >> 3;
    const int g    = zg & 7;
    const int y0   = (sp >> 2) * TS;
    const int x0   = (sp & 3) * TS;

    const float* xg = x + (size_t)(b * 256 + g * 32) * 4096;

    const int hh0 = (tid >= HP) ? 1 : 0;
    const int hp0 = tid - (hh0 ? HP : 0);
    const int hy0 = hp0 / HS, hx0 = hp0 - hy0 * HS;
    const int gy0 = y0 + hy0 - 3, gx0 = x0 + hx0 - 3;
    const bool ok0 = ((unsigned)gy0 < 64u) && ((unsigned)gx0 < 64u);

    const int hp1 = tid + 28;
    const int hy1 = hp1 / HS, hx1 = hp1 - hy1 * HS;
    const int gy1 = y0 + hy1 - 3, gx1 = x0 + hx1 - 3;
    const bool it1v = (tid < 2 * HP - 512);
    const bool ok1 = it1v && ((unsigned)gy1 < 64u) && ((unsigned)gx1 < 64u);

    float xr0[32], xr1[32];
    #pragma unroll
    for (int ci = 0; ci < 32; ++ci) { xr0[ci] = 0.f; xr1[ci] = 0.f; }
    if (ok0) {
        const float* xp = xg + gy0 * 64 + gx0;
        #pragma unroll
        for (int ci = 0; ci < 32; ++ci) xr0[ci] = xp[ci * 4096];
    }
    if (ok1) {
        const float* xp = xg + gy1 * 64 + gx1;
        #pragma unroll
        for (int ci = 0; ci < 32; ++ci) xr1[ci] = xp[ci * 4096];
    }

    {
        const int cp  = tid & 15;
        const int cog = tid >> 4;
        const int hh  = cog >> 4;
        const int co  = cog & 15;
        const int di  = (hh * 16 + cp) * 16 + co;
        const float2* wk2 = (const float2*)(wk + g * 1024);
        const float2* wv2 = (const float2*)(wv + g * 1024);
        const float2* wq2 = (const float2*)(wq + g * 1024);
        float2 a = wk2[tid]; s_w[di]        = pkrtz(a.x, a.y);
        float2 v = wv2[tid]; s_w[512 + di]  = pkrtz(v.x, v.y);
        float2 q = wq2[tid]; s_w[1024 + di] = pkrtz(q.x, q.y);
    }
    if (tid < 224) {
        int c = tid / KK, t = tid - c * KK;
        s_emb[tid] = (g < 4) ? row_emb[(g * 32 + c) * KK + t]
                             : col_emb[((g - 4) * 32 + c) * KK + t];
    }
    __syncthreads();

    {
        h2 xv2[16];
        #pragma unroll
        for (int cp = 0; cp < 16; ++cp) xv2[cp] = pkrtz(xr0[2 * cp], xr0[2 * cp + 1]);
        float accK[16], accV[16];
        #pragma unroll
        for (int c = 0; c < 16; ++c) { accK[c] = 0.f; accV[c] = 0.f; }
        const h2* wkp = s_w + hh0 * 256;
        const h2* wvp = s_w + 512 + hh0 * 256;
        #pragma unroll
        for (int cp = 0; cp < 16; ++cp) {
            h2 xv = xv2[cp];
            const uint4* wkr = (const uint4*)(wkp + cp * 16);
            const uint4* wvr = (const uint4*)(wvp + cp * 16);
            uint4 kw[4] = { wkr[0], wkr[1], wkr[2], wkr[3] };
            uint4 vw[4] = { wvr[0], wvr[1], wvr[2], wvr[3] };
            const unsigned* kwu = (const unsigned*)kw;
            const unsigned* vwu = (const unsigned*)vw;
            #pragma unroll
            for (int co = 0; co < 16; ++co) {
                accK[co] = dot2u(kwu[co], xv, accK[co]);
                accV[co] = dot2u(vwu[co], xv, accV[co]);
            }
        }
        unsigned* dk = s_ku + hp0 * KDW + hh0 * 8;
        unsigned* dv = s_vu + hp0 * KDW + hh0 * 8;
        #pragma unroll
        for (int j = 0; j < 4; ++j) {
            U32H a0, a1, b0, b1;
            a0.h = pkrtz(accK[4 * j],     accK[4 * j + 1]);
            a1.h = pkrtz(accK[4 * j + 2], accK[4 * j + 3]);
            b0.h = pkrtz(accV[4 * j],     accV[4 * j + 1]);
            b1.h = pkrtz(accV[4 * j + 2], accV[4 * j + 3]);
            ((uint2*)dk)[j] = make_uint2(a0.u, a1.u);
            ((uint2*)dv)[j] = make_uint2(b0.u, b1.u);
        }
    }
    if (it1v) {
        h2 xv2[16];
        #pragma unroll
        for (int cp = 0; cp < 16; ++cp) xv2[cp] = pkrtz(xr1[2 * cp], xr1[2 * cp + 1]);
        float accK[16], accV[16];
        #pragma unroll
        for (int c = 0; c < 16; ++c) { accK[c] = 0.f; accV[c] = 0.f; }
        const h2* wkp = s_w + 256;
        const h2* wvp = s_w + 512 + 256;
        #pragma unroll
        for (int cp = 0; cp < 16; ++cp) {
            h2 xv = xv2[cp];
            const uint4* wkr = (const uint4*)(wkp + cp * 16);
            const uint4* wvr = (const uint4*)(wvp + cp * 16);
            uint4 kw[4] = { wkr[0], wkr[1], wkr[2], wkr[3] };
            uint4 vw[4] = { wvr[0], wvr[1], wvr[2], wvr[3] };
            const unsigned* kwu = (const unsigned*)kw;
            const unsigned* vwu = (const unsigned*)vw;
            #pragma unroll
            for (int co = 0; co < 16; ++co) {
                accK[co] = dot2u(kwu[co], xv, accK[co]);
                accV[co] = dot2u(vwu[co], xv, accV[co]);
            }
        }
        unsigned* dk = s_ku + hp1 * KDW + 8;
        unsigned* dv = s_vu + hp1 * KDW + 8;
        #pragma unroll
        for (int j = 0; j < 4; ++j) {
            U32H a0, a1, b0, b1;
            a0.h = pkrtz(accK[4 * j],     accK[4 * j + 1]);
            a1.h = pkrtz(accK[4 * j + 2], accK[4 * j + 3]);
            b0.h = pkrtz(accV[4 * j],     accV[4 * j + 1]);
            b1.h = pkrtz(accV[4 * j + 2], accV[4 * j + 3]);
            ((uint2*)dk)[j] = make_uint2(a0.u, a1.u);
            ((uint2*)dv)[j] = make_uint2(b0.u, b1.u);
        }
    }

    const int p  = tid >> 1;
    const int h  = tid & 1;
    const int tx = p & 15, ty = p >> 4;
    const int yy = y0 + ty, xx = x0 + tx;
    float accQ[16];
    #pragma unroll
    for (int c = 0; c < 16; ++c) accQ[c] = 0.f;
    {
        const float* xp = xg + yy * 64 + xx;
        h2 xv2[16];
        #pragma unroll
        for (int cp = 0; cp < 16; ++cp)
            xv2[cp] = pkrtz(xp[(2 * cp) * 4096], xp[(2 * cp + 1) * 4096]);
        const h2* wqp = s_w + 1024 + h * 256;
        #pragma unroll
        for (int cp = 0; cp < 16; ++cp) {
            h2 xv = xv2[cp];
            const uint4* wqr = (const uint4*)(wqp + cp * 16);
            uint4 qw[4] = { wqr[0], wqr[1], wqr[2], wqr[3] };
            const unsigned* qwu = (const unsigned*)qw;
            #pragma unroll
            for (int co = 0; co < 16; ++co)
                accQ[co] = dot2u(qwu[co], xv, accQ[co]);
        }
    }

    float qe[KK];
    #pragma unroll
    for (int t = 0; t < KK; ++t) {
        float a = 0.f;
        #pragma unroll
        for (int c = 0; c < 16; ++c)
            a = fmaf(accQ[c], s_emb[(h * 16 + c) * KK + t], a);
        qe[t] = a;
    }
    #pragma unroll
    for (int t = 0; t < KK; ++t)
        qe[t] += pswap(qe[t]);

    h2 q2[8];
    #pragma unroll
    for (int j = 0; j < 8; ++j) q2[j] = pkrtz(accQ[2 * j], accQ[2 * j + 1]);

    __syncthreads();

    const int rowsel = (g < 4) ? 1 : 0;

    float lg[K2];
    const unsigned* kb = s_ku + h * 8;
    #pragma unroll
    for (int ki = 0; ki < KK; ++ki) {
        #pragma unroll
        for (int kj = 0; kj < KK; ++kj) {
            const uint2* kp = (const uint2*)(kb + ((ty + ki) * HS + tx + kj) * KDW);
            uint2 a0 = kp[0], a1 = kp[1], a2 = kp[2], a3 = kp[3];
            float p0 = 0.f;
            p0 = dot2u(a0.x, q2[0], p0); p0 = dot2u(a0.y, q2[1], p0);
            p0 = dot2u(a1.x, q2[2], p0); p0 = dot2u(a1.y, q2[3], p0);
            p0 = dot2u(a2.x, q2[4], p0); p0 = dot2u(a2.y, q2[5], p0);
            p0 = dot2u(a3.x, q2[6], p0); p0 = dot2u(a3.y, q2[7], p0);
            lg[ki * KK + kj] = p0 + pswap(p0) + (rowsel ? qe[ki] : qe[kj]);
        }
    }

    float m0 = lg[0], m1 = lg[1], m2 = lg[2], m3 = lg[3];
    #pragma unroll
    for (int t = 4; t < 48; t += 4) {
        m0 = fmaxf(m0, lg[t]);
        m1 = fmaxf(m1, lg[t + 1]);
        m2 = fmaxf(m2, lg[t + 2]);
        m3 = fmaxf(m3, lg[t + 3]);
    }
    const float mx = fmaxf(fmaxf(m0, m1), fmaxf(m2, fmaxf(m3, lg[48])));

    float s0 = 0.f, s1 = 0.f, s2 = 0.f, s3 = 0.f;
    #pragma unroll
    for (int t = 0; t < K2; ++t) {
        float pe = __expf(lg[t] - mx);
        lg[t] = pe;
        if ((t & 3) == 0) s0 += pe;
        else if ((t & 3) == 1) s1 += pe;
        else if ((t & 3) == 2) s2 += pe;
        else s3 += pe;
    }
    const float s = (s0 + s1) + (s2 + s3);

    __half2 o2[8];
    #pragma unroll
    for (int j = 0; j < 8; ++j) o2[j] = __float2half2_rn(0.f);

    const unsigned* vb = s_vu + h * 8;
    #pragma unroll
    for (int ki = 0; ki < KK; ++ki) {
        #pragma unroll
        for (int kj = 0; kj < KK; ++kj) {
            const uint2* vp = (const uint2*)(vb + ((ty + ki) * HS + tx + kj) * KDW);
            uint2 a0 = vp[0], a1 = vp[1], a2 = vp[2], a3 = vp[3];
            const __half2 pe2 = __float2half2_rn(lg[ki * KK + kj]);
            U32H c0, c1, c2, c3, c4, c5, c6, c7;
            c0.u = a0.x; c1.u = a0.y; c2.u = a1.x; c3.u = a1.y;
            c4.u = a2.x; c5.u = a2.y; c6.u = a3.x; c7.u = a3.y;
            o2[0] = __hfma2(c0.p, pe2, o2[0]);
            o2[1] = __hfma2(c1.p, pe2, o2[1]);
            o2[2] = __hfma2(c2.p, pe2, o2[2]);
            o2[3] = __hfma2(c3.p, pe2, o2[3]);
            o2[4] = __hfma2(c4.p, pe2, o2[4]);
            o2[5] = __hfma2(c5.p, pe2, o2[5]);
            o2[6] = __hfma2(c6.p, pe2, o2[6]);
            o2[7] = __hfma2(c7.p, pe2, o2[7]);
        }
    }

    const float inv = 1.0f / s;
    float* op = out + (size_t)(b * 256 + g * 32 + h * 16) * 4096 + yy * 64 + xx;
    #pragma unroll
    for (int j = 0; j < 8; ++j) {
        float2 f = __half22float2(o2[j]);
        op[(2 * j) * 4096]     = f.x * inv;
        op[(2 * j + 1) * 4096] = f.y * inv;
    }
}

extern "C" void kernel_launch(void* const* d_in, const int* in_sizes, int n_in,
                              void* d_out, int out_size, void* d_ws, size_t ws_size,
                              hipStream_t stream) {
    const float* x       = (const float*)d_in[0];
    const float* wq      = (const float*)d_in[1];
    const float* wk      = (const float*)d_in[2];
    const float* wv      = (const float*)d_in[3];
    const float* row_emb = (const float*)d_in[4];
    const float* col_emb = (const float*)d_in[5];
    float* out = (float*)d_out;

    const size_t seg = (size_t)32 * 4096 * 16;        // u32 per matrix
    const size_t need = 3 * seg * sizeof(unsigned);   // 25.2 MB

    if (ws_size >= need) {
        unsigned* kws = (unsigned*)d_ws;
        unsigned* vws = kws + seg;
        unsigned* qws = vws + seg;
        dim3 gridA(16, 32);
        proj_kernel<<<gridA, dim3(512), 0, stream>>>(x, wq, wk, wv, kws, vws, qws);
        dim3 gridB(4, 4, 32);
        attn_kernel<<<gridB, dim3(512), 0, stream>>>(kws, vws, qws, row_emb, col_emb, out);
    } else {
        dim3 grid(4, 4, 32);
        sasa_fused_kernel<<<grid, dim3(512), 0, stream>>>(x, wq, wk, wv, row_emb, col_emb, out);
    }
}